// Round 9
// baseline (2589.332 us; speedup 1.0000x reference)
//
#include <hip/hip_runtime.h>

typedef unsigned short u16;
typedef unsigned int u32;

#define NB 8
#define NPTS 4096
#define MSEL 2048
#define NCENT (NB*MSEL)
#define KNBR 64
#define FEAT 64
#define FIN 67
#define HH 64
#define FOUT 128
#define CAND_CAP 192

#define KP1 96     // layer-1 K padded to 3x32
#define SA 104     // feat A-buffer row stride (bf16 elems)
#define S2 72      // h1/h2 row stride

typedef __attribute__((ext_vector_type(8))) short short8;
typedef __attribute__((ext_vector_type(4))) float f32x4;

__device__ __forceinline__ float bf2f(u16 u) {
    union { u32 i; float f; } v; v.i = ((u32)u) << 16; return v.f;
}
__device__ __forceinline__ u16 f2bf(float f) {
    union { float f; u32 i; } v; v.f = f;
    u32 x = v.i;
    x += 0x7fffu + ((x >> 16) & 1u);
    return (u16)(x >> 16);
}
__device__ __forceinline__ void splitbf(float a, u16& hi, u16& lo) {
    u16 h = f2bf(a);
    hi = h;
    lo = f2bf(__fsub_rn(a, bf2f(h)));
}

// ---------------------------------------------------------------------------
// Fused lexicographic wave reduce: (M desc, I asc). 6 DPP stages; result in
// lane 63. bound_ctrl=false -> invalid source lanes keep own value (self-
// compare no-op). Same stage layout as the r7-verified wave_max_i.
// ---------------------------------------------------------------------------
#define LEX_STAGE(CTL)                                                        \
    {                                                                         \
        int uM = __builtin_amdgcn_update_dpp(M, M, CTL, 0xf, 0xf, false);     \
        int uI = __builtin_amdgcn_update_dpp(I, I, CTL, 0xf, 0xf, false);     \
        bool pr = (uM > M) || (uM == M && uI < I);                            \
        M = pr ? uM : M; I = pr ? uI : I;                                     \
    }
__device__ __forceinline__ void wave_lexred(int& M, int& I) {
    LEX_STAGE(0x111)   // row_shr 1
    LEX_STAGE(0x112)   // row_shr 2
    LEX_STAGE(0x114)   // row_shr 4
    LEX_STAGE(0x118)   // row_shr 8
    LEX_STAGE(0x142)   // row_bcast 15
    LEX_STAGE(0x143)   // row_bcast 31
}

// ---------------------------------------------------------------------------
// Kernel 1: exact FPS, 512 threads (8 pts/thread, 8 waves = 2/SIMD).
// Distance/argmax arithmetic bit-identical to verified r7/r8 (_rn ops, numpy
// sum order, strict-> first occurrence, max-value-then-min-index). One
// barrier/step, ping-pong slots, lane-63 register slot write, 8-slot
// broadcast scan.
// ---------------------------------------------------------------------------
__global__ __launch_bounds__(512) void fps_kernel(const float* __restrict__ pos,
        int* __restrict__ sel, float* __restrict__ pos_out,
        float* __restrict__ batch_out) {
    __shared__ float px[NPTS], py[NPTS], pz[NPTS];
    __shared__ int hist[MSEL];
    __shared__ int2 sMI[2][8];
    const int b = blockIdx.x, t = threadIdx.x;
    const int lane = t & 63, wid = t >> 6;
    const float* pb = pos + (long)b * NPTS * 3;

    for (int i = t; i < NPTS; i += 512) {
        px[i] = pb[i*3+0]; py[i] = pb[i*3+1]; pz[i] = pb[i*3+2];
    }
    __syncthreads();

    float rx[8], ry[8], rz[8], md[8];
    #pragma unroll
    for (int j = 0; j < 8; ++j) {
        int i = t + 512*j;
        rx[j] = px[i]; ry[j] = py[i]; rz[j] = pz[i];
        md[j] = __builtin_inff();
    }

    int cur = 0;
    float cx = px[0], cy = py[0], cz = pz[0];
    for (int s = 0; s < MSEL; ++s) {
        const int p = s & 1;
        if (t == 0) hist[s] = cur;
        float bv = -1.0f; int bi = 0;
        #pragma unroll
        for (int j = 0; j < 8; ++j) {
            float dx = __fsub_rn(rx[j], cx);
            float dy = __fsub_rn(ry[j], cy);
            float dz = __fsub_rn(rz[j], cz);
            float d  = __fadd_rn(__fadd_rn(__fmul_rn(dx,dx), __fmul_rn(dy,dy)),
                                 __fmul_rn(dz,dz));
            float m = fminf(md[j], d);
            md[j] = m;
            if (m > bv) { bv = m; bi = t + 512*j; }  // strict >: first occurrence
        }
        int M = (int)__float_as_uint(bv);             // bv >= 0 -> int-ordered
        int I = bi;
        wave_lexred(M, I);                            // lane 63: wave winner
        if (lane == 63) sMI[p][wid] = make_int2(M, I);
        __syncthreads();
        int2 v = sMI[p][0];
        int Mb = v.x, Ib = v.y;
        #pragma unroll
        for (int w = 1; w < 8; ++w) {
            int2 o = sMI[p][w];
            bool pr = (o.x > Mb) || (o.x == Mb && o.y < Ib);
            Mb = pr ? o.x : Mb; Ib = pr ? o.y : Ib;
        }
        cur = Ib;
        cx = px[cur]; cy = py[cur]; cz = pz[cur];
    }
    __syncthreads();
    for (int g = t; g < MSEL; g += 512) {
        int i = hist[g];
        int o = b * MSEL + g;
        sel[o] = i;
        pos_out[o*3+0] = px[i]; pos_out[o*3+1] = py[i]; pos_out[o*3+2] = pz[i];
        batch_out[o] = (float)b;
    }
}

// ---------------------------------------------------------------------------
// Kernel 1.5: weight pre-transform (unchanged, verified).
// ---------------------------------------------------------------------------
__global__ __launch_bounds__(256) void wcvt_kernel(const float* __restrict__ W1,
        const float* __restrict__ W2, const float* __restrict__ W3,
        u16* __restrict__ w1h, u16* __restrict__ w1l,
        u16* __restrict__ w2h, u16* __restrict__ w2l,
        u16* __restrict__ w3h, u16* __restrict__ w3l) {
    int t = blockIdx.x * 256 + threadIdx.x;
    if (t < 64*KP1) {
        int n = t / KP1, k = t % KP1;
        u16 h, l; splitbf((k < FIN) ? W1[(long)k*HH + n] : 0.0f, h, l);
        w1h[t] = h; w1l[t] = l;
    }
    if (t < 64*64) {
        int n = t / 64, k = t % 64;
        u16 h, l; splitbf(W2[(long)k*HH + n], h, l);
        w2h[t] = h; w2l[t] = l;
    }
    if (t < 128*64) {
        int n = t / 64, k = t % 64;
        u16 h, l; splitbf(W3[(long)k*FOUT + n], h, l);
        w3h[t] = h; w3l[t] = l;
    }
}

// ---------------------------------------------------------------------------
// Kernel 2: fused radius + PointNetConv + max-pool. MLP math byte-identical
// to verified r7/r8. LDS cuts only: CAND_CAP 384->192, f32 pool -> int
// atomicMax pool (r5-verified; relu>=0 makes int bits order-preserving).
// Static LDS ~47.4 KB -> target 3 blocks/CU.
// ---------------------------------------------------------------------------
__global__ __launch_bounds__(256) void conv_kernel(const float* __restrict__ x,
        const float* __restrict__ pos, const int* __restrict__ sel,
        const u16* __restrict__ w1h, const u16* __restrict__ w1l,
        const u16* __restrict__ w2h, const u16* __restrict__ w2l,
        const u16* __restrict__ w3h, const u16* __restrict__ w3l,
        const float* __restrict__ b1, const float* __restrict__ b2,
        const float* __restrict__ b3, float* __restrict__ xout) {
    __shared__ __align__(16) u16 fAh[64*SA], fAl[64*SA];
    __shared__ __align__(16) u16 h1h[64*S2], h1l[64*S2];
    __shared__ float cdv[CAND_CAP];
    __shared__ int   cixv[CAND_CAP];
    __shared__ int   snbr[KNBR];
    __shared__ int   pooli[FOUT];
    __shared__ int   sc[2];
    const int c = blockIdx.x, t = threadIdx.x;
    const int b = c >> 11;
    const int lane = t & 63, w = t >> 6;
    const float* pb = pos + (long)b * NPTS * 3;
    const int j0 = sel[c];
    const float qx = pb[j0*3+0], qy = pb[j0*3+1], qz = pb[j0*3+2];
    if (t == 0) { sc[0] = 0; sc[1] = 0; }
    if (t < FOUT) pooli[t] = 0;   // relu >= 0 and cnt >= 1 -> 0 is identity
    {
        u32* z1 = (u32*)fAh; u32* z2 = (u32*)fAl;
        for (int i = t; i < 64*SA/2; i += 256) { z1[i] = 0; z2[i] = 0; }
    }
    __syncthreads();

    const float R2 = (float)(0.15 * 0.15);
    for (int it = 0; it < NPTS/256; ++it) {
        int i = t + 256*it;
        float dx = __fsub_rn(qx, pb[i*3+0]);
        float dy = __fsub_rn(qy, pb[i*3+1]);
        float dz = __fsub_rn(qz, pb[i*3+2]);
        float d2 = __fadd_rn(__fadd_rn(__fmul_rn(dx,dx), __fmul_rn(dy,dy)),
                             __fmul_rn(dz,dz));
        if (d2 <= R2) {
            int slot = atomicAdd(&sc[0], 1);
            if (slot < CAND_CAP) { cdv[slot] = d2; cixv[slot] = i; }
        }
    }
    __syncthreads();
    int C = sc[0]; if (C > CAND_CAP) C = CAND_CAP;
    int cnt;
    if (C <= KNBR) {
        for (int e = t; e < C; e += 256) snbr[e] = cixv[e];
        cnt = C;
    } else {
        for (int e = t; e < C; e += 256) {
            float de = cdv[e]; int ie = cixv[e];
            int rank = 0;
            for (int f = 0; f < C; ++f) {
                float df = cdv[f]; int jf = cixv[f];
                rank += (df < de || (df == de && jf < ie)) ? 1 : 0;
            }
            if (rank < KNBR) {
                int slot = atomicAdd(&sc[1], 1);
                snbr[slot] = ie;
            }
        }
        cnt = KNBR;
    }
    __syncthreads();

    const int kk = t >> 2, sub = t & 3;
    if (kk < cnt) {
        int j = snbr[kk];
        const float4* xr4 = (const float4*)(x + ((long)b*NPTS + j) * FEAT);
        #pragma unroll
        for (int i = 0; i < 4; ++i) {
            int ci = sub*4 + i;
            float4 v = xr4[ci];
            u16 h0,l0,h1_,l1_,h2_,l2_,h3_,l3_;
            splitbf(v.x, h0, l0); splitbf(v.y, h1_, l1_);
            splitbf(v.z, h2_, l2_); splitbf(v.w, h3_, l3_);
            int o = kk*SA + ci*4;
            fAh[o+0]=h0; fAh[o+1]=h1_; fAh[o+2]=h2_; fAh[o+3]=h3_;
            fAl[o+0]=l0; fAl[o+1]=l1_; fAl[o+2]=l2_; fAl[o+3]=l3_;
        }
        if (sub < 3) {
            float qv = (sub == 0) ? qx : ((sub == 1) ? qy : qz);
            u16 h, l; splitbf(__fsub_rn(pb[j*3+sub], qv), h, l);
            fAh[kk*SA + 64 + sub] = h; fAl[kk*SA + 64 + sub] = l;
        }
    }
    __syncthreads();

    const int mrow = w * 16;
    const int mA = mrow + (lane & 15);
    const int kq = (lane >> 4) * 8;
    const int colc = lane & 15;
    const int rgrp = (lane >> 4) * 4;

    short8 a1h[3], a1l[3];
    #pragma unroll
    for (int i = 0; i < 3; ++i) {
        a1h[i] = *(const short8*)&fAh[mA*SA + i*32 + kq];
        a1l[i] = *(const short8*)&fAl[mA*SA + i*32 + kq];
    }
    #pragma unroll
    for (int nc = 0; nc < 4; ++nc) {
        int n = nc*16 + colc;
        float bb = b1[n];
        f32x4 acc = {bb, bb, bb, bb};
        short8 bh[3], bl[3];
        #pragma unroll
        for (int i = 0; i < 3; ++i) {
            bh[i] = *(const short8*)&w1h[n*KP1 + i*32 + kq];
            bl[i] = *(const short8*)&w1l[n*KP1 + i*32 + kq];
        }
        #pragma unroll
        for (int i = 0; i < 3; ++i)
            acc = __builtin_amdgcn_mfma_f32_16x16x32_bf16(a1h[i], bh[i], acc, 0,0,0);
        #pragma unroll
        for (int i = 0; i < 3; ++i)
            acc = __builtin_amdgcn_mfma_f32_16x16x32_bf16(a1h[i], bl[i], acc, 0,0,0);
        #pragma unroll
        for (int i = 0; i < 3; ++i)
            acc = __builtin_amdgcn_mfma_f32_16x16x32_bf16(a1l[i], bh[i], acc, 0,0,0);
        #pragma unroll
        for (int r = 0; r < 4; ++r) {
            u16 h, l; splitbf(fmaxf(acc[r], 0.0f), h, l);
            int m = mrow + rgrp + r;
            h1h[m*S2 + n] = h; h1l[m*S2 + n] = l;
        }
    }
    __syncthreads();

    short8 a2h[2], a2l[2];
    #pragma unroll
    for (int i = 0; i < 2; ++i) {
        a2h[i] = *(const short8*)&h1h[mA*S2 + i*32 + kq];
        a2l[i] = *(const short8*)&h1l[mA*S2 + i*32 + kq];
    }
    #pragma unroll
    for (int nc = 0; nc < 4; ++nc) {
        int n = nc*16 + colc;
        float bb = b2[n];
        f32x4 acc = {bb, bb, bb, bb};
        short8 bh[2], bl[2];
        #pragma unroll
        for (int i = 0; i < 2; ++i) {
            bh[i] = *(const short8*)&w2h[n*64 + i*32 + kq];
            bl[i] = *(const short8*)&w2l[n*64 + i*32 + kq];
        }
        #pragma unroll
        for (int i = 0; i < 2; ++i)
            acc = __builtin_amdgcn_mfma_f32_16x16x32_bf16(a2h[i], bh[i], acc, 0,0,0);
        #pragma unroll
        for (int i = 0; i < 2; ++i)
            acc = __builtin_amdgcn_mfma_f32_16x16x32_bf16(a2h[i], bl[i], acc, 0,0,0);
        #pragma unroll
        for (int i = 0; i < 2; ++i)
            acc = __builtin_amdgcn_mfma_f32_16x16x32_bf16(a2l[i], bh[i], acc, 0,0,0);
        #pragma unroll
        for (int r = 0; r < 4; ++r) {
            u16 h, l; splitbf(fmaxf(acc[r], 0.0f), h, l);
            int m = mrow + rgrp + r;
            fAh[m*S2 + n] = h; fAl[m*S2 + n] = l;
        }
    }
    __syncthreads();

    short8 a3h[2], a3l[2];
    #pragma unroll
    for (int i = 0; i < 2; ++i) {
        a3h[i] = *(const short8*)&fAh[mA*S2 + i*32 + kq];
        a3l[i] = *(const short8*)&fAl[mA*S2 + i*32 + kq];
    }
    #pragma unroll
    for (int nc = 0; nc < 8; ++nc) {
        int n = nc*16 + colc;
        float bb = b3[n];
        f32x4 acc = {bb, bb, bb, bb};
        short8 bh[2], bl[2];
        #pragma unroll
        for (int i = 0; i < 2; ++i) {
            bh[i] = *(const short8*)&w3h[n*64 + i*32 + kq];
            bl[i] = *(const short8*)&w3l[n*64 + i*32 + kq];
        }
        #pragma unroll
        for (int i = 0; i < 2; ++i)
            acc = __builtin_amdgcn_mfma_f32_16x16x32_bf16(a3h[i], bh[i], acc, 0,0,0);
        #pragma unroll
        for (int i = 0; i < 2; ++i)
            acc = __builtin_amdgcn_mfma_f32_16x16x32_bf16(a3h[i], bl[i], acc, 0,0,0);
        #pragma unroll
        for (int i = 0; i < 2; ++i)
            acc = __builtin_amdgcn_mfma_f32_16x16x32_bf16(a3l[i], bh[i], acc, 0,0,0);
        float v = 0.0f;
        #pragma unroll
        for (int r = 0; r < 4; ++r) {
            int m = mrow + rgrp + r;
            float hv = fmaxf(acc[r], 0.0f);
            v = (m < cnt) ? fmaxf(v, hv) : v;
        }
        v = fmaxf(v, __shfl_xor(v, 16, 64));
        v = fmaxf(v, __shfl_xor(v, 32, 64));
        if (lane < 16) atomicMax(&pooli[nc*16 + lane], __float_as_int(v));
    }
    __syncthreads();
    if (t < FOUT) xout[(long)c*FOUT + t] = __int_as_float(pooli[t]);
}

// ---------------------------------------------------------------------------
extern "C" void kernel_launch(void* const* d_in, const int* in_sizes, int n_in,
                              void* d_out, int out_size, void* d_ws, size_t ws_size,
                              hipStream_t stream) {
    const float* x   = (const float*)d_in[0];
    const float* pos = (const float*)d_in[1];
    const float* W1 = (const float*)d_in[3];
    const float* b1 = (const float*)d_in[4];
    const float* W2 = (const float*)d_in[5];
    const float* b2 = (const float*)d_in[6];
    const float* W3 = (const float*)d_in[7];
    const float* b3 = (const float*)d_in[8];

    float* out       = (float*)d_out;
    float* xout      = out;
    float* pos_out   = out + (long)NCENT * FOUT;
    float* batch_out = pos_out + (long)NCENT * 3;

    int* sel = (int*)d_ws;
    u16* w1h = (u16*)((char*)d_ws + 65536);
    u16* w1l = w1h + 64*KP1;
    u16* w2h = w1l + 64*KP1;
    u16* w2l = w2h + 64*64;
    u16* w3h = w2l + 64*64;
    u16* w3l = w3h + 128*64;

    wcvt_kernel<<<32, 256, 0, stream>>>(W1, W2, W3, w1h, w1l, w2h, w2l, w3h, w3l);
    fps_kernel<<<NB, 512, 0, stream>>>(pos, sel, pos_out, batch_out);
    conv_kernel<<<NCENT, 256, 0, stream>>>(x, pos, sel, w1h, w1l, w2h, w2l,
                                           w3h, w3l, b1, b2, b3, xout);
}

// Round 10
// 2314.661 us; speedup vs baseline: 1.1187x; 1.1187x over previous
//
#include <hip/hip_runtime.h>

typedef unsigned short u16;
typedef unsigned int u32;

#define NB 8
#define NPTS 4096
#define MSEL 2048
#define NCENT (NB*MSEL)
#define KNBR 64
#define FEAT 64
#define FIN 67
#define HH 64
#define FOUT 128
#define CAND_CAP 192

#define KP1 96     // layer-1 K padded to 3x32
#define SA 104     // feat A-buffer row stride (bf16 elems)
#define S2 72      // h1/h2 row stride

typedef __attribute__((ext_vector_type(8))) short short8;
typedef __attribute__((ext_vector_type(4))) float f32x4;

__device__ __forceinline__ float bf2f(u16 u) {
    union { u32 i; float f; } v; v.i = ((u32)u) << 16; return v.f;
}
__device__ __forceinline__ u16 f2bf(float f) {
    union { float f; u32 i; } v; v.f = f;
    u32 x = v.i;
    x += 0x7fffu + ((x >> 16) & 1u);
    return (u16)(x >> 16);
}
__device__ __forceinline__ void splitbf(float a, u16& hi, u16& lo) {
    u16 h = f2bf(a);
    hi = h;
    lo = f2bf(__fsub_rn(a, bf2f(h)));
}

// ---------------------------------------------------------------------------
// DPP wave-64 reductions (verified r7).
// ---------------------------------------------------------------------------
__device__ __forceinline__ int wave_max_i(int v) {
    int u;
    u = __builtin_amdgcn_update_dpp(v, v, 0x111, 0xf, 0xf, false); v = max(v, u);
    u = __builtin_amdgcn_update_dpp(v, v, 0x112, 0xf, 0xf, false); v = max(v, u);
    u = __builtin_amdgcn_update_dpp(v, v, 0x114, 0xf, 0xf, false); v = max(v, u);
    u = __builtin_amdgcn_update_dpp(v, v, 0x118, 0xf, 0xf, false); v = max(v, u);
    u = __builtin_amdgcn_update_dpp(v, v, 0x142, 0xf, 0xf, false); v = max(v, u);
    u = __builtin_amdgcn_update_dpp(v, v, 0x143, 0xf, 0xf, false); v = max(v, u);
    return __builtin_amdgcn_readlane(v, 63);
}
__device__ __forceinline__ int wave_min_i(int v) {
    int u;
    u = __builtin_amdgcn_update_dpp(v, v, 0x111, 0xf, 0xf, false); v = min(v, u);
    u = __builtin_amdgcn_update_dpp(v, v, 0x112, 0xf, 0xf, false); v = min(v, u);
    u = __builtin_amdgcn_update_dpp(v, v, 0x114, 0xf, 0xf, false); v = min(v, u);
    u = __builtin_amdgcn_update_dpp(v, v, 0x118, 0xf, 0xf, false); v = min(v, u);
    u = __builtin_amdgcn_update_dpp(v, v, 0x142, 0xf, 0xf, false); v = min(v, u);
    u = __builtin_amdgcn_update_dpp(v, v, 0x143, 0xf, 0xf, false); v = min(v, u);
    return __builtin_amdgcn_readlane(v, 63);
}

// ---------------------------------------------------------------------------
// Kernel 1: exact FPS == r7 (measured 1729 us) + ONE change: per-step global
// stores (t0) replaced by LDS hist + end flush, removing the vmcnt(0) drain
// the compiler emits before each per-step s_barrier. Distance/argmax
// arithmetic bit-identical (verified rounds 4-9).
// ---------------------------------------------------------------------------
__global__ __launch_bounds__(256) void fps_kernel(const float* __restrict__ pos,
        int* __restrict__ sel, float* __restrict__ pos_out,
        float* __restrict__ batch_out) {
    __shared__ float px[NPTS], py[NPTS], pz[NPTS];
    __shared__ int hist[MSEL];
    __shared__ int sM[2][4], sI[2][4];
    __shared__ float sX[2][4], sY[2][4], sZ[2][4];
    const int b = blockIdx.x, t = threadIdx.x;
    const int wid = t >> 6;
    const float* pb = pos + (long)b * NPTS * 3;

    for (int i = t; i < NPTS; i += 256) {
        px[i] = pb[i*3+0]; py[i] = pb[i*3+1]; pz[i] = pb[i*3+2];
    }
    __syncthreads();

    float rx[16], ry[16], rz[16], md[16];
    #pragma unroll
    for (int j = 0; j < 16; ++j) {
        int i = t + 256*j;
        rx[j] = px[i]; ry[j] = py[i]; rz[j] = pz[i];
        md[j] = __builtin_inff();
    }

    int cur = 0;
    float cx = px[0], cy = py[0], cz = pz[0];
    for (int s = 0; s < MSEL; ++s) {
        const int p = s & 1;
        if (t == 0) hist[s] = cur;
        float bv = -1.0f; int bi = 0;
        #pragma unroll
        for (int j = 0; j < 16; ++j) {
            float dx = __fsub_rn(rx[j], cx);
            float dy = __fsub_rn(ry[j], cy);
            float dz = __fsub_rn(rz[j], cz);
            float d  = __fadd_rn(__fadd_rn(__fmul_rn(dx,dx), __fmul_rn(dy,dy)),
                                 __fmul_rn(dz,dz));
            float m = fminf(md[j], d);
            md[j] = m;
            if (m > bv) { bv = m; bi = t + 256*j; }   // strict >: first occurrence
        }
        const int fb = (int)__float_as_uint(bv);       // bv >= 0 -> int-ordered
        const int Mw = wave_max_i(fb);
        const int cnd = (fb == Mw) ? bi : 0x7fffffff;
        const int Iw = wave_min_i(cnd);                // wave argmax, min index
        if (t == (Iw & 255)) {                         // owner carries coords
            int j = Iw >> 8;
            sM[p][wid] = Mw; sI[p][wid] = Iw;
            sX[p][wid] = rx[j]; sY[p][wid] = ry[j]; sZ[p][wid] = rz[j];
        }
        __syncthreads();
        int M = sM[p][0], I = sI[p][0];
        float nx = sX[p][0], ny = sY[p][0], nz = sZ[p][0];
        #pragma unroll
        for (int w = 1; w < 4; ++w) {
            int Mo = sM[p][w], Io = sI[p][w];
            if (Mo > M || (Mo == M && Io < I)) {
                M = Mo; I = Io; nx = sX[p][w]; ny = sY[p][w]; nz = sZ[p][w];
            }
        }
        cur = I; cx = nx; cy = ny; cz = nz;
    }
    __syncthreads();
    for (int g = t; g < MSEL; g += 256) {
        int i = hist[g];
        int o = b * MSEL + g;
        sel[o] = i;
        pos_out[o*3+0] = px[i]; pos_out[o*3+1] = py[i]; pos_out[o*3+2] = pz[i];
        batch_out[o] = (float)b;
    }
}

// ---------------------------------------------------------------------------
// Kernel 1.5: weight pre-transform (unchanged, verified).
// ---------------------------------------------------------------------------
__global__ __launch_bounds__(256) void wcvt_kernel(const float* __restrict__ W1,
        const float* __restrict__ W2, const float* __restrict__ W3,
        u16* __restrict__ w1h, u16* __restrict__ w1l,
        u16* __restrict__ w2h, u16* __restrict__ w2l,
        u16* __restrict__ w3h, u16* __restrict__ w3l) {
    int t = blockIdx.x * 256 + threadIdx.x;
    if (t < 64*KP1) {
        int n = t / KP1, k = t % KP1;
        u16 h, l; splitbf((k < FIN) ? W1[(long)k*HH + n] : 0.0f, h, l);
        w1h[t] = h; w1l[t] = l;
    }
    if (t < 64*64) {
        int n = t / 64, k = t % 64;
        u16 h, l; splitbf(W2[(long)k*HH + n], h, l);
        w2h[t] = h; w2l[t] = l;
    }
    if (t < 128*64) {
        int n = t / 64, k = t % 64;
        u16 h, l; splitbf(W3[(long)k*FOUT + n], h, l);
        w3h[t] = h; w3l[t] = l;
    }
}

// ---------------------------------------------------------------------------
// Kernel 2: fused radius + PointNetConv + max-pool, BARRIER-FREE MLP.
// The MLP is row-independent and every wave's staging rows, A-frag rows, and
// C/D rows coincide (16w..16w+15) -> inter-stage __syncthreads replaced by
// wave-local __threadfence_block() (DS pipe per-wave in-order; fence pins
// compiler order). h2 overwrites the h1 buffer's OWN rows (no cross-wave
// stride aliasing while waves drift). Gather/rank-select and all MFMA
// arithmetic byte-identical to r7/r8/r9 (absmax must stay 0.015625).
// ---------------------------------------------------------------------------
__global__ __launch_bounds__(256) void conv_kernel(const float* __restrict__ x,
        const float* __restrict__ pos, const int* __restrict__ sel,
        const u16* __restrict__ w1h, const u16* __restrict__ w1l,
        const u16* __restrict__ w2h, const u16* __restrict__ w2l,
        const u16* __restrict__ w3h, const u16* __restrict__ w3l,
        const float* __restrict__ b1, const float* __restrict__ b2,
        const float* __restrict__ b3, float* __restrict__ xout) {
    __shared__ __align__(16) u16 fAh[64*SA], fAl[64*SA];   // staged features
    __shared__ __align__(16) u16 h1h[64*S2], h1l[64*S2];   // h1, then h2 (same rows)
    __shared__ float cdv[CAND_CAP];
    __shared__ int   cixv[CAND_CAP];
    __shared__ int   snbr[KNBR];
    __shared__ float poolw[4][FOUT];
    __shared__ int   sc[2];
    const int c = blockIdx.x, t = threadIdx.x;
    const int b = c >> 11;
    const int lane = t & 63, w = t >> 6;
    const int colc = lane & 15;
    const float* pb = pos + (long)b * NPTS * 3;
    const int j0 = sel[c];
    const float qx = pb[j0*3+0], qy = pb[j0*3+1], qz = pb[j0*3+2];

    // prefetch biases early (hide global latency behind gather)
    float bias1[4], bias2[4], bias3[8];
    #pragma unroll
    for (int nc = 0; nc < 4; ++nc) { bias1[nc] = b1[nc*16+colc]; bias2[nc] = b2[nc*16+colc]; }
    #pragma unroll
    for (int nc = 0; nc < 8; ++nc) bias3[nc] = b3[nc*16+colc];

    if (t == 0) { sc[0] = 0; sc[1] = 0; }
    __syncthreads();

    // ---- radius gather (bit-exact; verified r4-r9)
    const float R2 = (float)(0.15 * 0.15);
    for (int it = 0; it < NPTS/256; ++it) {
        int i = t + 256*it;
        float dx = __fsub_rn(qx, pb[i*3+0]);
        float dy = __fsub_rn(qy, pb[i*3+1]);
        float dz = __fsub_rn(qz, pb[i*3+2]);
        float d2 = __fadd_rn(__fadd_rn(__fmul_rn(dx,dx), __fmul_rn(dy,dy)),
                             __fmul_rn(dz,dz));
        if (d2 <= R2) {
            int slot = atomicAdd(&sc[0], 1);
            if (slot < CAND_CAP) { cdv[slot] = d2; cixv[slot] = i; }
        }
    }
    __syncthreads();
    int C = sc[0]; if (C > CAND_CAP) C = CAND_CAP;
    int cnt;
    if (C <= KNBR) {
        for (int e = t; e < C; e += 256) snbr[e] = cixv[e];
        cnt = C;
    } else {
        for (int e = t; e < C; e += 256) {
            float de = cdv[e]; int ie = cixv[e];
            int rank = 0;
            for (int f = 0; f < C; ++f) {
                float df = cdv[f]; int jf = cixv[f];
                rank += (df < de || (df == de && jf < ie)) ? 1 : 0;
            }
            if (rank < KNBR) {
                int slot = atomicAdd(&sc[1], 1);
                snbr[slot] = ie;
            }
        }
        cnt = KNBR;
    }
    __syncthreads();   // last block-wide barrier before the pool combine

    // ---- stage features (wave-local rows); zero the K-pad cols 67..99
    const int kk = t >> 2, sub = t & 3;
    if (kk < cnt) {
        int j = snbr[kk];
        const float4* xr4 = (const float4*)(x + ((long)b*NPTS + j) * FEAT);
        #pragma unroll
        for (int i = 0; i < 4; ++i) {
            int ci = sub*4 + i;
            float4 v = xr4[ci];
            u16 h0,l0,h1_,l1_,h2_,l2_,h3_,l3_;
            splitbf(v.x, h0, l0); splitbf(v.y, h1_, l1_);
            splitbf(v.z, h2_, l2_); splitbf(v.w, h3_, l3_);
            int o = kk*SA + ci*4;
            fAh[o+0]=h0; fAh[o+1]=h1_; fAh[o+2]=h2_; fAh[o+3]=h3_;
            fAl[o+0]=l0; fAl[o+1]=l1_; fAl[o+2]=l2_; fAl[o+3]=l3_;
        }
        if (sub < 3) {
            float qv = (sub == 0) ? qx : ((sub == 1) ? qy : qz);
            u16 h, l; splitbf(__fsub_rn(pb[j*3+sub], qv), h, l);
            fAh[kk*SA + 64 + sub] = h; fAl[kk*SA + 64 + sub] = l;
        } else {
            fAh[kk*SA + 67] = 0; fAl[kk*SA + 67] = 0;
        }
        u32* zh = (u32*)&fAh[kk*SA + 68];
        u32* zl = (u32*)&fAl[kk*SA + 68];
        #pragma unroll
        for (int i2 = 0; i2 < 4; ++i2) { zh[sub + 4*i2] = 0; zl[sub + 4*i2] = 0; }
    }
    __threadfence_block();   // wave-local cross-lane LDS visibility

    const int mrow = w * 16;
    const int mA = mrow + (lane & 15);
    const int kq = (lane >> 4) * 8;
    const int rgrp = (lane >> 4) * 4;

    // ---- layer 1: 96(67) -> 64
    short8 a1h[3], a1l[3];
    #pragma unroll
    for (int i = 0; i < 3; ++i) {
        a1h[i] = *(const short8*)&fAh[mA*SA + i*32 + kq];
        a1l[i] = *(const short8*)&fAl[mA*SA + i*32 + kq];
    }
    #pragma unroll
    for (int nc = 0; nc < 4; ++nc) {
        int n = nc*16 + colc;
        float bb = bias1[nc];
        f32x4 acc = {bb, bb, bb, bb};
        short8 bh[3], bl[3];
        #pragma unroll
        for (int i = 0; i < 3; ++i) {
            bh[i] = *(const short8*)&w1h[n*KP1 + i*32 + kq];
            bl[i] = *(const short8*)&w1l[n*KP1 + i*32 + kq];
        }
        #pragma unroll
        for (int i = 0; i < 3; ++i)
            acc = __builtin_amdgcn_mfma_f32_16x16x32_bf16(a1h[i], bh[i], acc, 0,0,0);
        #pragma unroll
        for (int i = 0; i < 3; ++i)
            acc = __builtin_amdgcn_mfma_f32_16x16x32_bf16(a1h[i], bl[i], acc, 0,0,0);
        #pragma unroll
        for (int i = 0; i < 3; ++i)
            acc = __builtin_amdgcn_mfma_f32_16x16x32_bf16(a1l[i], bh[i], acc, 0,0,0);
        #pragma unroll
        for (int r = 0; r < 4; ++r) {
            u16 h, l; splitbf(fmaxf(acc[r], 0.0f), h, l);
            int m = mrow + rgrp + r;
            h1h[m*S2 + n] = h; h1l[m*S2 + n] = l;
        }
    }
    __threadfence_block();

    // ---- layer 2: 64 -> 64 (frags to regs first, h2 overwrites same rows)
    short8 a2h[2], a2l[2];
    #pragma unroll
    for (int i = 0; i < 2; ++i) {
        a2h[i] = *(const short8*)&h1h[mA*S2 + i*32 + kq];
        a2l[i] = *(const short8*)&h1l[mA*S2 + i*32 + kq];
    }
    #pragma unroll
    for (int nc = 0; nc < 4; ++nc) {
        int n = nc*16 + colc;
        float bb = bias2[nc];
        f32x4 acc = {bb, bb, bb, bb};
        short8 bh[2], bl[2];
        #pragma unroll
        for (int i = 0; i < 2; ++i) {
            bh[i] = *(const short8*)&w2h[n*64 + i*32 + kq];
            bl[i] = *(const short8*)&w2l[n*64 + i*32 + kq];
        }
        #pragma unroll
        for (int i = 0; i < 2; ++i)
            acc = __builtin_amdgcn_mfma_f32_16x16x32_bf16(a2h[i], bh[i], acc, 0,0,0);
        #pragma unroll
        for (int i = 0; i < 2; ++i)
            acc = __builtin_amdgcn_mfma_f32_16x16x32_bf16(a2h[i], bl[i], acc, 0,0,0);
        #pragma unroll
        for (int i = 0; i < 2; ++i)
            acc = __builtin_amdgcn_mfma_f32_16x16x32_bf16(a2l[i], bh[i], acc, 0,0,0);
        #pragma unroll
        for (int r = 0; r < 4; ++r) {
            u16 h, l; splitbf(fmaxf(acc[r], 0.0f), h, l);
            int m = mrow + rgrp + r;
            h1h[m*S2 + n] = h; h1l[m*S2 + n] = l;
        }
    }
    __threadfence_block();

    // ---- layer 3: 64 -> 128 + fused relu + masked max-pool (per-wave)
    short8 a3h[2], a3l[2];
    #pragma unroll
    for (int i = 0; i < 2; ++i) {
        a3h[i] = *(const short8*)&h1h[mA*S2 + i*32 + kq];
        a3l[i] = *(const short8*)&h1l[mA*S2 + i*32 + kq];
    }
    #pragma unroll
    for (int nc = 0; nc < 8; ++nc) {
        int n = nc*16 + colc;
        float bb = bias3[nc];
        f32x4 acc = {bb, bb, bb, bb};
        short8 bh[2], bl[2];
        #pragma unroll
        for (int i = 0; i < 2; ++i) {
            bh[i] = *(const short8*)&w3h[n*64 + i*32 + kq];
            bl[i] = *(const short8*)&w3l[n*64 + i*32 + kq];
        }
        #pragma unroll
        for (int i = 0; i < 2; ++i)
            acc = __builtin_amdgcn_mfma_f32_16x16x32_bf16(a3h[i], bh[i], acc, 0,0,0);
        #pragma unroll
        for (int i = 0; i < 2; ++i)
            acc = __builtin_amdgcn_mfma_f32_16x16x32_bf16(a3h[i], bl[i], acc, 0,0,0);
        #pragma unroll
        for (int i = 0; i < 2; ++i)
            acc = __builtin_amdgcn_mfma_f32_16x16x32_bf16(a3l[i], bh[i], acc, 0,0,0);
        float v = 0.0f;   // relu >= 0 and cnt >= 1 -> 0 is identity
        #pragma unroll
        for (int r = 0; r < 4; ++r) {
            int m = mrow + rgrp + r;
            float hv = fmaxf(acc[r], 0.0f);
            v = (m < cnt) ? fmaxf(v, hv) : v;
        }
        v = fmaxf(v, __shfl_xor(v, 16, 64));
        v = fmaxf(v, __shfl_xor(v, 32, 64));
        if (lane < 16) poolw[w][nc*16 + lane] = v;
    }
    __syncthreads();
    if (t < FOUT) {
        float v = fmaxf(fmaxf(poolw[0][t], poolw[1][t]),
                        fmaxf(poolw[2][t], poolw[3][t]));
        xout[(long)c*FOUT + t] = v;
    }
}

// ---------------------------------------------------------------------------
extern "C" void kernel_launch(void* const* d_in, const int* in_sizes, int n_in,
                              void* d_out, int out_size, void* d_ws, size_t ws_size,
                              hipStream_t stream) {
    const float* x   = (const float*)d_in[0];
    const float* pos = (const float*)d_in[1];
    const float* W1 = (const float*)d_in[3];
    const float* b1 = (const float*)d_in[4];
    const float* W2 = (const float*)d_in[5];
    const float* b2 = (const float*)d_in[6];
    const float* W3 = (const float*)d_in[7];
    const float* b3 = (const float*)d_in[8];

    float* out       = (float*)d_out;
    float* xout      = out;
    float* pos_out   = out + (long)NCENT * FOUT;
    float* batch_out = pos_out + (long)NCENT * 3;

    int* sel = (int*)d_ws;
    u16* w1h = (u16*)((char*)d_ws + 65536);
    u16* w1l = w1h + 64*KP1;
    u16* w2h = w1l + 64*KP1;
    u16* w2l = w2h + 64*64;
    u16* w3h = w2l + 64*64;
    u16* w3l = w3h + 128*64;

    wcvt_kernel<<<32, 256, 0, stream>>>(W1, W2, W3, w1h, w1l, w2h, w2l, w3h, w3l);
    fps_kernel<<<NB, 256, 0, stream>>>(pos, sel, pos_out, batch_out);
    conv_kernel<<<NCENT, 256, 0, stream>>>(x, pos, sel, w1h, w1l, w2h, w2l,
                                           w3h, w3l, b1, b2, b3, xout);
}